// Round 5
// baseline (189.160 us; speedup 1.0000x reference)
//
#include <hip/hip_runtime.h>
#include <stdint.h>

// ModulatedConv2D: B=8, IC=OC=512, K=3, H=W=32
// y[b,oc,p] = rsqrt(dacc[b,oc]+1e-8) * conv( x[b,ic,p]*sm[b,ic], conv_w )
// Conv: implicit GEMM, 32x32x16 f16 MFMA, 512 blocks (2/CU) for TLP.

#define B_   8
#define IC_  512
#define OC_  512

static constexpr float RC_DENSE = 0.04419417382415922f;   // 1/sqrt(512)
static constexpr float RC_CONV  = 0.014731391274719739f;  // 1/sqrt(4608)

typedef _Float16 half8    __attribute__((ext_vector_type(8)));
typedef float    floatx16 __attribute__((ext_vector_type(16)));

// async global->LDS, 16B per lane; LDS dest = wave-uniform base + lane*16
__device__ __forceinline__ void g2l(const void* g, void* l) {
  __builtin_amdgcn_global_load_lds(
      (const __attribute__((address_space(1))) void*)g,
      (__attribute__((address_space(3))) void*)l, 16, 0, 0);
}

// ---- sm = (w@(RC_DENSE*dw) + db + 1)*RC_CONV ; sm2 = sm^2 ; zero dacc ----
__global__ __launch_bounds__(256) void style_kernel(
    const float* __restrict__ wv, const float* __restrict__ dw,
    const float* __restrict__ db, float* __restrict__ sm,
    float* __restrict__ sm2, float* __restrict__ dacc) {
  const int b = blockIdx.y;
  const int i = blockIdx.x * 64 + (threadIdx.x & 63);
  const int jg = threadIdx.x >> 6;
  __shared__ float red[4][64];
  float p = 0.f;
  for (int j = jg * 128; j < jg * 128 + 128; ++j)
    p += wv[b * IC_ + j] * dw[(size_t)j * IC_ + i];
  red[jg][threadIdx.x & 63] = p;
  __syncthreads();
  if (threadIdx.x < 64) {
    float s = red[0][threadIdx.x] + red[1][threadIdx.x] +
              red[2][threadIdx.x] + red[3][threadIdx.x];
    s = s * RC_DENSE + db[i] + 1.0f;
    float v = s * RC_CONV;
    sm[b * IC_ + i] = v;
    sm2[b * IC_ + i] = v * v;
    dacc[b * IC_ + i] = 0.f;   // wts (later in stream) accumulates into this
  }
}

// ---- Wtf[by][icb][t 9][kk 2][kq 2][oc 64][8] (f16); dacc += sm2 . sum_t cw^2 ----
__global__ __launch_bounds__(256) void wts_kernel(
    const float* __restrict__ cw, const float* __restrict__ sm2,
    _Float16* __restrict__ Wtf, float* __restrict__ dacc) {
  const int by = blockIdx.x, icb = blockIdx.y;
  const int oc0 = by * 64, ic0 = icb * 32;
  const int oc = threadIdx.x & 63, g = threadIdx.x >> 6;
  __shared__ _Float16 LA[18432];
  __shared__ float red[4][64];
  float sq[8] = {};
  for (int m = 0; m < 72; ++m) {
    int r = g + 4 * m;                 // r = t*32 + icl, r%4 == g
    int t = r >> 5, icl = r & 31;
    float v = cw[(size_t)(t * IC_ + ic0 + icl) * OC_ + oc0 + oc];  // 64-contig
    sq[m & 7] += v * v;                // icl = g + 4*(m&7)
    int kk = (icl >> 4) & 1, kq2 = (icl >> 3) & 1, j = icl & 7;
    LA[(((t * 2 + kk) * 2 + kq2) * 64 + oc) * 8 + j] = (_Float16)v;
  }
  __syncthreads();
  _Float16* dst = Wtf + (size_t)(by * 16 + icb) * 18432;
  for (int i = 0; i < 9; ++i) {        // 2304 chunks, coalesced b128
    int c = i * 256 + threadIdx.x;
    *(half8*)(dst + (size_t)c * 8) = *(const half8*)&LA[c * 8];
  }
  // demod partial: dacc[b][oc] += sum_{ic in tile} sm2[b][ic] * sq
  for (int b = 0; b < 8; ++b) {
    float p = 0.f;
    for (int s2 = 0; s2 < 8; ++s2)
      p += sm2[b * IC_ + ic0 + g + 4 * s2] * sq[s2];
    red[g][oc] = p;
    __syncthreads();
    if (g == 0)
      atomicAdd(&dacc[b * OC_ + oc0 + oc],
                red[0][oc] + red[1][oc] + red[2][oc] + red[3][oc]);
    __syncthreads();
  }
}

// ---- xsp[b][icb 16][r 34][kk 2][kq 2][C 34][8 halfs] = f16(x*sm), padded ----
__global__ __launch_bounds__(256) void xsp_kernel(
    const float* __restrict__ x, const float* __restrict__ sm,
    _Float16* __restrict__ xsp) {
  const int h = blockIdx.x, b = blockIdx.y;
  __shared__ _Float16 Xt[32 * 520];    // [w][512 ic + 8 pad]
  const int tid = threadIdx.x;
  for (int k = 0; k < 16; ++k) {
    int idx = k * 256 + tid;           // 512 ic * 8 w-quads
    int ic = idx >> 3, wc = (idx & 7) * 4;
    float4 v = *(const float4*)&x[((size_t)(b * IC_ + ic) * 32 + h) * 32 + wc];
    float s = sm[b * IC_ + ic];
    Xt[(wc + 0) * 520 + ic] = (_Float16)(v.x * s);
    Xt[(wc + 1) * 520 + ic] = (_Float16)(v.y * s);
    Xt[(wc + 2) * 520 + ic] = (_Float16)(v.z * s);
    Xt[(wc + 3) * 520 + ic] = (_Float16)(v.w * s);
  }
  __syncthreads();
  _Float16* xb = xsp + (size_t)b * 16 * 36992;
  const int r = h + 1;
  half8 z = {};
  for (int it = 0; it < 9; ++it) {     // 16 icb * 4 kkq * 34 C = 2176 chunks
    int c = it * 256 + tid;
    if (c < 2176) {
      int icb = c / 136, rem = c - 136 * icb, kkq = rem / 34, C = rem - 34 * kkq;
      half8 val = z;
      if (C != 0 && C != 33)
        val = *(const half8*)&Xt[(C - 1) * 520 + icb * 32 + kkq * 8];
      *(half8*)&xb[(size_t)icb * 36992 + (size_t)r * 1088 + kkq * 272 + C * 8] = val;
    }
  }
  if (h == 0 || h == 31) {             // zero top/bottom padded rows
    const int rz = (h == 0) ? 0 : 33;
    for (int it = 0; it < 9; ++it) {
      int c = it * 256 + tid;
      if (c < 2176) {
        int icb = c / 136, rem = c - 136 * icb, kkq = rem / 34, C = rem - 34 * kkq;
        *(half8*)&xb[(size_t)icb * 36992 + (size_t)rz * 1088 + kkq * 272 + C * 8] = z;
      }
    }
  }
}

// ---- conv: block 64oc x 128px (4 rows), grid 8x8x8 = 512 (2 blocks/CU) ----
// Wave (wm,wn): 32oc x 64px (2 rows), acc[2]x16. Per wave/icb: 18 A b128
// (global, L1/L2), 24 X b128 (LDS), 36 MFMA 32x32x16. 2 waves/SIMD TLP.
__global__ __launch_bounds__(256, 2) void conv_kernel(
    const _Float16* __restrict__ Wtf,   // [8 by][16 icb][18432 halfs]
    const _Float16* __restrict__ xsp,   // [8 b][16 icb][34 r][2 kk][2 kq][34 C][8]
    const float* __restrict__ dacc,     // [8][512] demod sum-of-squares
    float* __restrict__ out) {          // [8][512][32][32]
  const int bx = blockIdx.x, by = blockIdx.y, b = blockIdx.z;
  const int tid = threadIdx.x, lane = tid & 63, w = tid >> 6;
  const int wm = w & 1, wn = w >> 1;    // wn: which 2-row half
  const int n = lane & 31, kq = lane >> 5;
  const int h0 = bx * 4;                // output rows h0..h0+3; padded h0..h0+5

  __shared__ _Float16 Xb[2][6528];      // 816 chunks x 8 halfs = 13056 B each

  const _Float16* gX = xsp + (size_t)b * 16 * 36992 + (size_t)h0 * 1088;
  const _Float16* gA = Wtf + (size_t)(by * 16) * 18432;
  const int aoff = kq * 512 + (wm * 32 + n) * 8;

  // prologue: stage X(0)
  for (int i = 0; i < 4; ++i) {
    int c = i * 256 + tid;
    if (c < 816) g2l(gX + (size_t)c * 8, &Xb[0][c * 8]);
  }

  floatx16 acc[2] = {};
  for (int icb = 0; icb < 16; ++icb) {
    const int cur = icb & 1;
    __syncthreads();                    // X(cur) staged & visible
    if (icb < 15) {                     // prefetch X(icb+1) into alt buffer
      const _Float16* gX1 = gX + (size_t)(icb + 1) * 36992;
      for (int i = 0; i < 4; ++i) {
        int c = i * 256 + tid;
        if (c < 816) g2l(gX1 + (size_t)c * 8, &Xb[cur ^ 1][c * 8]);
      }
    }
    // A frags for this icb straight from global (L1 dedups wn-twin wave)
    const _Float16* gAi = gA + (size_t)icb * 18432 + aoff;
    half8 a[9][2];
#pragma unroll
    for (int t = 0; t < 9; ++t)
#pragma unroll
      for (int kk = 0; kk < 2; ++kk)
        a[t][kk] = *(const half8*)(gAi + (t * 2 + kk) * 1024);
    // X frags: staged rows s = 2*wn .. 2*wn+3, col n+kw, k-half kk
    const _Float16* Xp = &Xb[cur][0] + (wn * 2) * 1088 + kq * 272 + n * 8;
#pragma unroll
    for (int s = 0; s < 4; ++s) {
#pragma unroll
      for (int kw = 0; kw < 3; ++kw) {
#pragma unroll
        for (int kk = 0; kk < 2; ++kk) {
          half8 xv = *(const half8*)(Xp + s * 1088 + kk * 544 + kw * 8);
#pragma unroll
          for (int kh = 0; kh < 3; ++kh) {
            int j = s - kh;
            if (j >= 0 && j < 2)
              acc[j] = __builtin_amdgcn_mfma_f32_32x32x16_f16(
                  a[kh * 3 + kw][kk], xv, acc[j], 0, 0, 0);
          }
        }
      }
    }
  }

  // epilogue: dv = rsqrt(dacc+1e-8); D col(px)=n, row(oc)=(rg&3)+8*(rg>>2)+4*kq
  const int oc0 = by * 64 + wm * 32;
  const int r0 = h0 + wn * 2;
#pragma unroll
  for (int rg = 0; rg < 16; ++rg) {
    const int row = (rg & 3) + 8 * (rg >> 2) + 4 * kq;
    const float dv = rsqrtf(dacc[b * OC_ + oc0 + row] + 1e-8f);
    float* op = out + ((size_t)b * OC_ + oc0 + row) * 1024 + r0 * 32 + n;
    op[0]  = acc[0][rg] * dv;
    op[32] = acc[1][rg] * dv;
  }
}

extern "C" void kernel_launch(void* const* d_in, const int* in_sizes, int n_in,
                              void* d_out, int out_size, void* d_ws, size_t ws_size,
                              hipStream_t stream) {
  const float* x       = (const float*)d_in[0];
  const float* w       = (const float*)d_in[1];
  const float* conv_w  = (const float*)d_in[2];
  const float* dense_w = (const float*)d_in[3];
  const float* dense_b = (const float*)d_in[4];
  float* out = (float*)d_out;

  char* ws = (char*)d_ws;
  float*    sm   = (float*)ws;                         // 16 KB
  float*    sm2  = (float*)(ws + (16 << 10));          // 16 KB
  float*    dacc = (float*)(ws + (32 << 10));          // 16 KB
  _Float16* Wtf  = (_Float16*)(ws + (48 << 10));                 // 4,718,592 B
  _Float16* xsp  = (_Float16*)(ws + (48 << 10) + 4718592);       // 9,469,952 B

  style_kernel<<<dim3(8, B_), 256, 0, stream>>>(w, dense_w, dense_b, sm, sm2, dacc);
  wts_kernel<<<dim3(8, 16), 256, 0, stream>>>(conv_w, sm2, Wtf, dacc);
  xsp_kernel<<<dim3(32, B_), 256, 0, stream>>>(x, sm, xsp);
  conv_kernel<<<dim3(8, 8, B_), 256, 0, stream>>>(Wtf, xsp, dacc, out);
}

// Round 6
// 151.734 us; speedup vs baseline: 1.2467x; 1.2467x over previous
//
#include <hip/hip_runtime.h>
#include <stdint.h>

// ModulatedConv2D: B=8, IC=OC=512, K=3, H=W=32
// y[b,oc,p] = rsqrt(dacc[b,oc]+1e-8) * conv( x[b,ic,p]*sm[b,ic], conv_w )
// Conv: implicit GEMM, 32x32x16 f16 MFMA, split-K=2 (icb 0-7 / 8-15),
// 512 blocks (2/CU, 2 waves/SIMD), fp32 atomicAdd combine into zeroed out.

#define B_   8
#define IC_  512
#define OC_  512

static constexpr float RC_DENSE = 0.04419417382415922f;   // 1/sqrt(512)
static constexpr float RC_CONV  = 0.014731391274719739f;  // 1/sqrt(4608)

typedef _Float16 half8    __attribute__((ext_vector_type(8)));
typedef float    floatx16 __attribute__((ext_vector_type(16)));

// async global->LDS, 16B per lane; LDS dest = wave-uniform base + lane*16
__device__ __forceinline__ void g2l(const void* g, void* l) {
  __builtin_amdgcn_global_load_lds(
      (const __attribute__((address_space(1))) void*)g,
      (__attribute__((address_space(3))) void*)l, 16, 0, 0);
}

// ---- sm = (w@(RC_DENSE*dw) + db + 1)*RC_CONV ; sm2 = sm^2 ; zero dacc ----
__global__ __launch_bounds__(256) void style_kernel(
    const float* __restrict__ wv, const float* __restrict__ dw,
    const float* __restrict__ db, float* __restrict__ sm,
    float* __restrict__ sm2, float* __restrict__ dacc) {
  const int b = blockIdx.y;
  const int i = blockIdx.x * 64 + (threadIdx.x & 63);
  const int jg = threadIdx.x >> 6;
  __shared__ float red[4][64];
  float p = 0.f;
  for (int j = jg * 128; j < jg * 128 + 128; ++j)
    p += wv[b * IC_ + j] * dw[(size_t)j * IC_ + i];
  red[jg][threadIdx.x & 63] = p;
  __syncthreads();
  if (threadIdx.x < 64) {
    float s = red[0][threadIdx.x] + red[1][threadIdx.x] +
              red[2][threadIdx.x] + red[3][threadIdx.x];
    s = s * RC_DENSE + db[i] + 1.0f;
    float v = s * RC_CONV;
    sm[b * IC_ + i] = v;
    sm2[b * IC_ + i] = v * v;
    dacc[b * IC_ + i] = 0.f;   // prep (later in stream) accumulates into this
  }
}

// ---- fused prep: blocks 0..127 = Wtf+dacc ; blocks 128..383 = xsp ----
// Wtf[by][icb][t 9][kk 2][kq 2][oc 64][8] (f16); dacc += sm2 . sum_t cw^2
// xsp[b][icb 16][r 34][kk 2][kq 2][C 34][8 halfs] = f16(x*sm), zero-padded
__global__ __launch_bounds__(256) void prep_kernel(
    const float* __restrict__ cw, const float* __restrict__ sm2,
    const float* __restrict__ x, const float* __restrict__ sm,
    _Float16* __restrict__ Wtf, float* __restrict__ dacc,
    _Float16* __restrict__ xsp) {
  __shared__ __align__(16) char smem[45056];
  const int bid = blockIdx.x;
  const int tid = threadIdx.x;
  if (bid < 128) {
    // ---------------- Wtf + dacc role ----------------
    _Float16* LA = (_Float16*)smem;                 // 36864 B
    float* redall = (float*)(smem + 36864);         // 8192 B
    const int by = bid >> 4, icb = bid & 15;
    const int oc0 = by * 64, ic0 = icb * 32;
    const int oc = tid & 63, g = tid >> 6;
    float sq[8] = {};
    for (int m = 0; m < 72; ++m) {
      int r = g + 4 * m;                 // r = t*32 + icl, r%4 == g
      int t = r >> 5, icl = r & 31;
      float v = cw[(size_t)(t * IC_ + ic0 + icl) * OC_ + oc0 + oc];
      sq[m & 7] += v * v;                // icl = g + 4*(m&7)
      int kk = (icl >> 4) & 1, kq2 = (icl >> 3) & 1, j = icl & 7;
      LA[(((t * 2 + kk) * 2 + kq2) * 64 + oc) * 8 + j] = (_Float16)v;
    }
    // demod partials (uses per-thread sq, no barrier needed yet)
    for (int b = 0; b < 8; ++b) {
      float p = 0.f;
      for (int s2 = 0; s2 < 8; ++s2)
        p += sm2[b * IC_ + ic0 + g + 4 * s2] * sq[s2];
      redall[(b * 4 + g) * 64 + oc] = p;
    }
    __syncthreads();
    _Float16* dst = Wtf + (size_t)(by * 16 + icb) * 18432;
    for (int i = 0; i < 9; ++i) {        // 2304 chunks, coalesced b128
      int c = i * 256 + tid;
      *(half8*)(dst + (size_t)c * 8) = *(const half8*)&LA[c * 8];
    }
    const int bb = tid >> 6;             // 0..3 -> handles b = bb, bb+4
    for (int h = 0; h < 2; ++h) {
      int b = bb + h * 4;
      float s = redall[(b * 4 + 0) * 64 + oc] + redall[(b * 4 + 1) * 64 + oc] +
                redall[(b * 4 + 2) * 64 + oc] + redall[(b * 4 + 3) * 64 + oc];
      atomicAdd(&dacc[b * OC_ + oc0 + oc], s);
    }
  } else {
    // ---------------- xsp role ----------------
    _Float16* Xt = (_Float16*)smem;      // 32*520*2 = 33280 B
    const int r2 = bid - 128;
    const int h = r2 >> 3, b = r2 & 7;
    for (int k = 0; k < 16; ++k) {
      int idx = k * 256 + tid;           // 512 ic * 8 w-quads
      int ic = idx >> 3, wc = (idx & 7) * 4;
      float4 v = *(const float4*)&x[((size_t)(b * IC_ + ic) * 32 + h) * 32 + wc];
      float s = sm[b * IC_ + ic];
      Xt[(wc + 0) * 520 + ic] = (_Float16)(v.x * s);
      Xt[(wc + 1) * 520 + ic] = (_Float16)(v.y * s);
      Xt[(wc + 2) * 520 + ic] = (_Float16)(v.z * s);
      Xt[(wc + 3) * 520 + ic] = (_Float16)(v.w * s);
    }
    __syncthreads();
    _Float16* xb = xsp + (size_t)b * 16 * 36992;
    const int r = h + 1;
    half8 z = {};
    for (int it = 0; it < 9; ++it) {     // 16 icb * 4 kkq * 34 C = 2176 chunks
      int c = it * 256 + tid;
      if (c < 2176) {
        int icb = c / 136, rem = c - 136 * icb, kkq = rem / 34, C = rem - 34 * kkq;
        half8 val = z;
        if (C != 0 && C != 33)
          val = *(const half8*)&Xt[(C - 1) * 520 + icb * 32 + kkq * 8];
        *(half8*)&xb[(size_t)icb * 36992 + (size_t)r * 1088 + kkq * 272 + C * 8] = val;
      }
    }
    if (h == 0 || h == 31) {             // zero top/bottom padded rows
      const int rz = (h == 0) ? 0 : 33;
      for (int it = 0; it < 9; ++it) {
        int c = it * 256 + tid;
        if (c < 2176) {
          int icb = c / 136, rem = c - 136 * icb, kkq = rem / 34, C = rem - 34 * kkq;
          *(half8*)&xb[(size_t)icb * 36992 + (size_t)rz * 1088 + kkq * 272 + C * 8] = z;
        }
      }
    }
  }
}

// ---- conv: split-K=2. Block 64oc x 256px (8 rows), 4 waves (wm2 x wn2),
// wave 32oc x 128px (4 rows), acc[4]x16, an[] register prefetch (round-4
// proven). Grid 4bx x 8by x 16(b,ks) = 512 blocks = 2/CU, 2 waves/SIMD.
__global__ __launch_bounds__(256) void conv_kernel(
    const _Float16* __restrict__ Wtf,   // [8 by][16 icb][18432 halfs]
    const _Float16* __restrict__ xsp,   // [8 b][16 icb][34 r][2 kk][2 kq][34 C][8]
    const float* __restrict__ dacc,     // [8][512] demod sum-of-squares
    float* __restrict__ out) {          // [8][512][32][32], pre-zeroed
  const int bx = blockIdx.x, by = blockIdx.y;
  const int b = blockIdx.z >> 1, ks = blockIdx.z & 1;
  const int tid = threadIdx.x, lane = tid & 63, w = tid >> 6;
  const int wm = w & 1, wn = w >> 1;
  const int n = lane & 31, kq = lane >> 5;
  const int h0 = bx * 8;                // padded rows h0 .. h0+9 staged

  __shared__ _Float16 Xb[2][10880];     // 21760 B each

  const _Float16* gX = xsp + ((size_t)b * 16 + ks * 8) * 36992 + (size_t)h0 * 1088;
  const _Float16* gA = Wtf + (size_t)(by * 16 + ks * 8) * 18432;
  const int aoff = kq * 512 + (wm * 32 + n) * 8;

  // prologue: stage X(0), load A(0)
  for (int i = 0; i < 6; ++i) {
    int c = i * 256 + tid;
    if (c < 1360) g2l(gX + (size_t)c * 8, &Xb[0][c * 8]);
  }
  half8 a[9][2], an[9][2];
#pragma unroll
  for (int t = 0; t < 9; ++t)
#pragma unroll
    for (int kk = 0; kk < 2; ++kk)
      a[t][kk] = *(const half8*)(gA + aoff + (t * 2 + kk) * 1024);

  floatx16 acc[4] = {};
  for (int icb = 0; icb < 8; ++icb) {
    const int cur = icb & 1;
    __syncthreads();                    // X(cur) staged & visible
    if (icb < 7) {                      // prefetch icb+1 (regs for A, LDS for X)
      const _Float16* gA1 = gA + (size_t)(icb + 1) * 18432 + aoff;
#pragma unroll
      for (int t = 0; t < 9; ++t)
#pragma unroll
        for (int kk = 0; kk < 2; ++kk)
          an[t][kk] = *(const half8*)(gA1 + (t * 2 + kk) * 1024);
      const _Float16* gX1 = gX + (size_t)(icb + 1) * 36992;
      for (int i = 0; i < 6; ++i) {
        int c = i * 256 + tid;
        if (c < 1360) g2l(gX1 + (size_t)c * 8, &Xb[cur ^ 1][c * 8]);
      }
    }
    // compute: X frag at staged row (wn*4+rr), col n+kw, k-half kk
    const _Float16* Xp = &Xb[cur][0] + (wn * 4) * 1088 + kq * 272 + n * 8;
#pragma unroll
    for (int rr = 0; rr < 6; ++rr) {
#pragma unroll
      for (int kw = 0; kw < 3; ++kw) {
#pragma unroll
        for (int kk = 0; kk < 2; ++kk) {
          half8 xv = *(const half8*)(Xp + rr * 1088 + kk * 544 + kw * 8);
#pragma unroll
          for (int kh = 0; kh < 3; ++kh) {
            int pr = rr - kh;
            if (pr >= 0 && pr < 4)
              acc[pr] = __builtin_amdgcn_mfma_f32_32x32x16_f16(
                  a[kh * 3 + kw][kk], xv, acc[pr], 0, 0, 0);
          }
        }
      }
    }
#pragma unroll
    for (int t = 0; t < 9; ++t) { a[t][0] = an[t][0]; a[t][1] = an[t][1]; }
  }

  // epilogue: dv = rsqrt(dacc+1e-8); atomicAdd partial (out pre-zeroed).
  // D col(px)=n, row(oc)=(rg&3)+8*(rg>>2)+4*kq
  const int oc0 = by * 64 + wm * 32;
  const int r0 = h0 + wn * 4;
#pragma unroll
  for (int rg = 0; rg < 16; ++rg) {
    const int row = (rg & 3) + 8 * (rg >> 2) + 4 * kq;
    const float dv = rsqrtf(dacc[b * OC_ + oc0 + row] + 1e-8f);
    float* op = out + ((size_t)b * OC_ + oc0 + row) * 1024 + r0 * 32 + n;
#pragma unroll
    for (int pr = 0; pr < 4; ++pr)
      atomicAdd(&op[pr * 32], acc[pr][rg] * dv);
  }
}

extern "C" void kernel_launch(void* const* d_in, const int* in_sizes, int n_in,
                              void* d_out, int out_size, void* d_ws, size_t ws_size,
                              hipStream_t stream) {
  const float* x       = (const float*)d_in[0];
  const float* w       = (const float*)d_in[1];
  const float* conv_w  = (const float*)d_in[2];
  const float* dense_w = (const float*)d_in[3];
  const float* dense_b = (const float*)d_in[4];
  float* out = (float*)d_out;

  char* ws = (char*)d_ws;
  float*    sm   = (float*)ws;                         // 16 KB
  float*    sm2  = (float*)(ws + (16 << 10));          // 16 KB
  float*    dacc = (float*)(ws + (32 << 10));          // 16 KB
  _Float16* Wtf  = (_Float16*)(ws + (48 << 10));                 // 4,718,592 B
  _Float16* xsp  = (_Float16*)(ws + (48 << 10) + 4718592);       // 9,469,952 B

  hipMemsetAsync(out, 0, (size_t)B_ * OC_ * 1024 * sizeof(float), stream);
  style_kernel<<<dim3(8, B_), 256, 0, stream>>>(w, dense_w, dense_b, sm, sm2, dacc);
  prep_kernel<<<384, 256, 0, stream>>>(conv_w, sm2, x, sm, Wtf, dacc, xsp);
  conv_kernel<<<dim3(4, 8, 16), 256, 0, stream>>>(Wtf, xsp, dacc, out);
}

// Round 7
// 151.730 us; speedup vs baseline: 1.2467x; 1.0000x over previous
//
#include <hip/hip_runtime.h>
#include <stdint.h>

// ModulatedConv2D: B=8, IC=OC=512, K=3, H=W=32
// 2 dispatches: prep (weights repack + demod partials + modulated input repack,
// style computed inline per block) and conv (implicit GEMM, 32x32x16 f16 MFMA,
// 512 blocks = 2/CU = 2 waves/SIMD, register A-prefetch, plain stores).

#define B_   8
#define IC_  512
#define OC_  512

static constexpr float RC_DENSE = 0.04419417382415922f;   // 1/sqrt(512)
static constexpr float RC_CONV  = 0.014731391274719739f;  // 1/sqrt(4608)

typedef _Float16 half8    __attribute__((ext_vector_type(8)));
typedef float    floatx16 __attribute__((ext_vector_type(16)));

// async global->LDS, 16B per lane; LDS dest = wave-uniform base + lane*16
__device__ __forceinline__ void g2l(const void* g, void* l) {
  __builtin_amdgcn_global_load_lds(
      (const __attribute__((address_space(1))) void*)g,
      (__attribute__((address_space(3))) void*)l, 16, 0, 0);
}

// ---------------- prep: 384 blocks ----------------
// bid<128 (wts role, by=bid>>4, icb=bid&15):
//   style slice sm2[8][32] inline; Wtf[by][icb][t9][kk2][kq2][oc64][8] f16;
//   dpart[icb][b][oc] = sum_{icl} sm2 * sum_t cw^2   (no atomics)
// bid>=128 (xsp role, b=(bid-128)>>5, icc=(bid-128)&31):
//   style slice sm[16] inline; xsp[b][icb][r34][kk2][kq2][C34][8] f16, padded
__global__ __launch_bounds__(256) void prep_kernel(
    const float* __restrict__ cw, const float* __restrict__ x,
    const float* __restrict__ wv, const float* __restrict__ dw,
    const float* __restrict__ db,
    _Float16* __restrict__ Wtf, float* __restrict__ dpart,
    _Float16* __restrict__ xsp) {
  __shared__ __align__(16) char smem[51456];
  const int bid = blockIdx.x;
  const int tid = threadIdx.x;
  if (bid < 128) {
    // ---------------- wts + dpart role ----------------
    _Float16* LA = (_Float16*)smem;                  // 36864 B
    float* redall = (float*)(smem + 36864);          // 8192 B (32 x 64)
    float* sm2l   = (float*)(smem + 36864 + 8192);   // 1024 B (8 b x 32 icl)
    const int by = bid >> 4, icb = bid & 15;
    const int oc0 = by * 64, ic0 = icb * 32;
    // phase 1: style^2 for 8 b x 32 icl (one dot per thread)
    {
      const int bb = tid >> 5, icl = tid & 31;
      float dot = 0.f;
      for (int j = 0; j < 512; ++j)
        dot += wv[bb * IC_ + j] * dw[(size_t)j * IC_ + ic0 + icl];
      float s = (dot * RC_DENSE + db[ic0 + icl] + 1.0f) * RC_CONV;
      sm2l[bb * 32 + icl] = s * s;
    }
    __syncthreads();
    // phase 2: load cw tile, square-sums, fragment repack
    const int oc = tid & 63, g = tid >> 6;
    float sq[8] = {};
    for (int m = 0; m < 72; ++m) {
      int r = g + 4 * m;                 // r = t*32 + icl, icl = g + 4*(m&7)
      int t = r >> 5, icl = r & 31;
      float v = cw[(size_t)(t * IC_ + ic0 + icl) * OC_ + oc0 + oc];
      sq[m & 7] += v * v;
      int kk = (icl >> 4) & 1, kq2 = (icl >> 3) & 1, j = icl & 7;
      LA[(((t * 2 + kk) * 2 + kq2) * 64 + oc) * 8 + j] = (_Float16)v;
    }
    for (int bb = 0; bb < 8; ++bb) {
      float p = 0.f;
      for (int s2 = 0; s2 < 8; ++s2)
        p += sm2l[bb * 32 + g + 4 * s2] * sq[s2];
      redall[(bb * 4 + g) * 64 + oc] = p;
    }
    __syncthreads();
    _Float16* dst = Wtf + (size_t)(by * 16 + icb) * 18432;
    for (int i = 0; i < 9; ++i) {        // 2304 b128 chunks, coalesced
      int c = i * 256 + tid;
      *(half8*)(dst + (size_t)c * 8) = *(const half8*)&LA[c * 8];
    }
    const int bb3 = tid >> 6;            // handles b = bb3, bb3+4
    for (int h2 = 0; h2 < 2; ++h2) {
      int b = bb3 + h2 * 4;
      float s = redall[(b * 4 + 0) * 64 + oc] + redall[(b * 4 + 1) * 64 + oc] +
                redall[(b * 4 + 2) * 64 + oc] + redall[(b * 4 + 3) * 64 + oc];
      dpart[(size_t)icb * 4096 + b * OC_ + oc0 + oc] = s;
    }
  } else {
    // ---------------- xsp role ----------------
    _Float16* Xt = (_Float16*)smem;                  // 1024 px x 24 pitch = 49152 B
    float* red2  = (float*)(smem + 49152);           // 1024 B (16 jg x 16 icl)
    float* sml   = (float*)(smem + 49152 + 1024);    // 64 B
    const int rb = bid - 128;
    const int b = rb >> 5, icc = rb & 31;
    const int ic0 = icc * 16, icb = icc >> 1, kk = icc & 1;
    // phase 1: style for 16 ic (16 threads x 16 j-groups)
    {
      const int icl = tid & 15, jg = tid >> 4;
      float p = 0.f;
      for (int j = jg * 32; j < jg * 32 + 32; ++j)
        p += wv[b * IC_ + j] * dw[(size_t)j * IC_ + ic0 + icl];
      red2[jg * 16 + icl] = p;
    }
    __syncthreads();
    if (tid < 16) {
      float s = 0.f;
      for (int jg = 0; jg < 16; ++jg) s += red2[jg * 16 + tid];
      sml[tid] = (s * RC_DENSE + db[ic0 + tid] + 1.0f) * RC_CONV;
    }
    __syncthreads();
    // phase 2: scaled f16 transpose into Xt[px][ic_local] (pitch 24)
    for (int ic = 0; ic < 16; ++ic) {
      const float s = sml[ic];
      const int h = tid >> 3, w4 = (tid & 7) * 4;
      float4 v = *(const float4*)&x[((size_t)(b * IC_ + ic0 + ic) * 32 + h) * 32 + w4];
      const int px = h * 32 + w4;
      Xt[(px + 0) * 24 + ic] = (_Float16)(v.x * s);
      Xt[(px + 1) * 24 + ic] = (_Float16)(v.y * s);
      Xt[(px + 2) * 24 + ic] = (_Float16)(v.z * s);
      Xt[(px + 3) * 24 + ic] = (_Float16)(v.w * s);
    }
    __syncthreads();
    // phase 3: write our (icb, kk) slice of xsp incl. zero borders
    _Float16* xb = xsp + ((size_t)(b * 16 + icb)) * 36992 + kk * 544;
    half8 z = {};
    for (int it = 0; it < 10; ++it) {
      int c = it * 256 + tid;            // 2 kq x 34 r x 34 C = 2312 chunks
      if (c < 2312) {
        int kq = c / 1156, rem = c - kq * 1156, r = rem / 34, C = rem - r * 34;
        half8 val = z;
        if (r != 0 && r != 33 && C != 0 && C != 33)
          val = *(const half8*)&Xt[((r - 1) * 32 + (C - 1)) * 24 + kq * 8];
        *(half8*)&xb[(size_t)r * 1088 + kq * 272 + C * 8] = val;
      }
    }
  }
}

// ---- conv: block 64oc x 128px (4 rows), grid 8x8x8 = 512 (2/CU, 2 w/SIMD) ----
// Wave (wm,wn): 32oc x 64px (2 rows), acc[2]x16. Per wave/icb: 18 A b128
// (global, an[] register prefetch), 24 X b128 (LDS), 36 MFMA 32x32x16.
__global__ __launch_bounds__(256, 2) void conv_kernel(
    const _Float16* __restrict__ Wtf,   // [8 by][16 icb][18432 halfs]
    const _Float16* __restrict__ xsp,   // [8 b][16 icb][34 r][2 kk][2 kq][34 C][8]
    const float* __restrict__ dpart,    // [16 icb][8 b][512 oc]
    float* __restrict__ out) {          // [8][512][32][32]
  const int bx = blockIdx.x, by = blockIdx.y, b = blockIdx.z;
  const int tid = threadIdx.x, lane = tid & 63, w = tid >> 6;
  const int wm = w & 1, wn = w >> 1;    // wn: which 2-row half
  const int n = lane & 31, kq = lane >> 5;
  const int h0 = bx * 4;                // output rows h0..h0+3; padded h0..h0+5

  __shared__ _Float16 Xb[2][6528];      // 816 chunks x 8 halfs = 13056 B each
  __shared__ float redd[4][64];
  __shared__ float dvl[64];

  const _Float16* gX = xsp + (size_t)b * 16 * 36992 + (size_t)h0 * 1088;
  const _Float16* gA = Wtf + (size_t)(by * 16) * 18432;
  const int aoff = kq * 512 + (wm * 32 + n) * 8;

  // prologue: stage X(0), load A(0)
  for (int i = 0; i < 4; ++i) {
    int c = i * 256 + tid;
    if (c < 816) g2l(gX + (size_t)c * 8, &Xb[0][c * 8]);
  }
  half8 a[9][2], an[9][2];
#pragma unroll
  for (int t = 0; t < 9; ++t)
#pragma unroll
    for (int kk = 0; kk < 2; ++kk)
      a[t][kk] = *(const half8*)(gA + aoff + (t * 2 + kk) * 1024);

  floatx16 acc[2] = {};
  for (int icb = 0; icb < 16; ++icb) {
    const int cur = icb & 1;
    __syncthreads();                    // X(cur) staged & visible
    if (icb < 15) {                     // prefetch icb+1: A->regs, X->LDS
      const _Float16* gA1 = gA + (size_t)(icb + 1) * 18432 + aoff;
#pragma unroll
      for (int t = 0; t < 9; ++t)
#pragma unroll
        for (int kk = 0; kk < 2; ++kk)
          an[t][kk] = *(const half8*)(gA1 + (t * 2 + kk) * 1024);
      const _Float16* gX1 = gX + (size_t)(icb + 1) * 36992;
      for (int i = 0; i < 4; ++i) {
        int c = i * 256 + tid;
        if (c < 816) g2l(gX1 + (size_t)c * 8, &Xb[cur ^ 1][c * 8]);
      }
    }
    // compute: X frag at staged row (wn*2+s), col n+kw, k-half kk
    const _Float16* Xp = &Xb[cur][0] + (wn * 2) * 1088 + kq * 272 + n * 8;
#pragma unroll
    for (int s = 0; s < 4; ++s) {
#pragma unroll
      for (int kw = 0; kw < 3; ++kw) {
#pragma unroll
        for (int kk = 0; kk < 2; ++kk) {
          half8 xv = *(const half8*)(Xp + s * 1088 + kk * 544 + kw * 8);
#pragma unroll
          for (int kh = 0; kh < 3; ++kh) {
            int j = s - kh;
            if (j >= 0 && j < 2)
              acc[j] = __builtin_amdgcn_mfma_f32_32x32x16_f16(
                  a[kh * 3 + kw][kk], xv, acc[j], 0, 0, 0);
          }
        }
      }
    }
#pragma unroll
    for (int t = 0; t < 9; ++t) { a[t][0] = an[t][0]; a[t][1] = an[t][1]; }
  }

  // epilogue: reduce dpart over 16 icb -> dv[64] in LDS, then plain stores
  __syncthreads();
  {
    const int oc_l = tid & 63, ig = tid >> 6;
    float s = 0.f;
    for (int k = 0; k < 4; ++k)
      s += dpart[(size_t)(ig * 4 + k) * 4096 + b * OC_ + by * 64 + oc_l];
    redd[ig][oc_l] = s;
  }
  __syncthreads();
  if (tid < 64)
    dvl[tid] = rsqrtf(redd[0][tid] + redd[1][tid] + redd[2][tid] +
                      redd[3][tid] + 1e-8f);
  __syncthreads();
  // D col(px)=n, row(oc)=(rg&3)+8*(rg>>2)+4*kq
  const int oc0 = by * 64 + wm * 32;
  const int r0 = h0 + wn * 2;
#pragma unroll
  for (int rg = 0; rg < 16; ++rg) {
    const int row = (rg & 3) + 8 * (rg >> 2) + 4 * kq;
    const float dv = dvl[wm * 32 + row];
    float* op = out + ((size_t)b * OC_ + oc0 + row) * 1024 + r0 * 32 + n;
    op[0]  = acc[0][rg] * dv;
    op[32] = acc[1][rg] * dv;
  }
}

extern "C" void kernel_launch(void* const* d_in, const int* in_sizes, int n_in,
                              void* d_out, int out_size, void* d_ws, size_t ws_size,
                              hipStream_t stream) {
  const float* x       = (const float*)d_in[0];
  const float* w       = (const float*)d_in[1];
  const float* conv_w  = (const float*)d_in[2];
  const float* dense_w = (const float*)d_in[3];
  const float* dense_b = (const float*)d_in[4];
  float* out = (float*)d_out;

  char* ws = (char*)d_ws;
  float*    dpart = (float*)ws;                        // 16*8*512*4 = 256 KB
  _Float16* Wtf   = (_Float16*)(ws + (256 << 10));               // 4,718,592 B
  _Float16* xsp   = (_Float16*)(ws + (256 << 10) + 4718592);     // 9,469,952 B

  prep_kernel<<<384, 256, 0, stream>>>(conv_w, x, w, dense_w, dense_b,
                                       Wtf, dpart, xsp);
  conv_kernel<<<dim3(8, 8, B_), 256, 0, stream>>>(Wtf, xsp, dpart, out);
}

// Round 8
// 130.127 us; speedup vs baseline: 1.4537x; 1.1660x over previous
//
#include <hip/hip_runtime.h>
#include <stdint.h>

// ModulatedConv2D: B=8, IC=OC=512, K=3, H=W=32
// 3 dispatches: style (sm, sm2), prep (Wtf repack + dpart demod partials +
// xsp repack), conv (implicit GEMM, 32x32x16 f16 MFMA, grid x=by so all
// blocks sharing a weight by-slice land on one XCD -> A is L2-resident).

#define B_   8
#define IC_  512
#define OC_  512

static constexpr float RC_DENSE = 0.04419417382415922f;   // 1/sqrt(512)
static constexpr float RC_CONV  = 0.014731391274719739f;  // 1/sqrt(4608)

typedef _Float16 half8    __attribute__((ext_vector_type(8)));
typedef float    floatx16 __attribute__((ext_vector_type(16)));

// async global->LDS, 16B per lane; LDS dest = wave-uniform base + lane*16
__device__ __forceinline__ void g2l(const void* g, void* l) {
  __builtin_amdgcn_global_load_lds(
      (const __attribute__((address_space(1))) void*)g,
      (__attribute__((address_space(3))) void*)l, 16, 0, 0);
}

// ---- sm = (w@(RC_DENSE*dw) + db + 1)*RC_CONV ; sm2 = sm^2 ----
__global__ __launch_bounds__(256) void style_kernel(
    const float* __restrict__ wv, const float* __restrict__ dw,
    const float* __restrict__ db, float* __restrict__ sm,
    float* __restrict__ sm2) {
  const int b = blockIdx.y;
  const int i = blockIdx.x * 64 + (threadIdx.x & 63);
  const int jg = threadIdx.x >> 6;
  __shared__ float red[4][64];
  float p = 0.f;
  for (int j = jg * 128; j < jg * 128 + 128; ++j)
    p += wv[b * IC_ + j] * dw[(size_t)j * IC_ + i];
  red[jg][threadIdx.x & 63] = p;
  __syncthreads();
  if (threadIdx.x < 64) {
    float s = red[0][threadIdx.x] + red[1][threadIdx.x] +
              red[2][threadIdx.x] + red[3][threadIdx.x];
    s = s * RC_DENSE + db[i] + 1.0f;
    float v = s * RC_CONV;
    sm[b * IC_ + i] = v;
    sm2[b * IC_ + i] = v * v;
  }
}

// ---------------- prep: 512 blocks (2/CU) ----------------
// bid<256 (wts role): 32oc x 32ic half-tile; Wtf[by][icb][ktq 36][oc64][8] f16
//   + dpart[icb][b][oc] = sum_icl sm2 * sum_t cw^2 (disjoint oc, no atomics)
// bid>=256 (xsp role): per (b,h) row; xsp[b][icb][r34][kk2][kq2][C34][8] f16
__global__ __launch_bounds__(256) void prep_kernel(
    const float* __restrict__ cw, const float* __restrict__ x,
    const float* __restrict__ sm, const float* __restrict__ sm2,
    _Float16* __restrict__ Wtf, float* __restrict__ dpart,
    _Float16* __restrict__ xsp) {
  __shared__ __align__(16) char smem[33280];
  const int bid = blockIdx.x;
  const int tid = threadIdx.x;
  if (bid < 256) {
    // ---------------- wts + dpart role ----------------
    _Float16* LA = (_Float16*)smem;                // 18432 B
    float* redall = (float*)(smem + 18432);        // 8192 B (8b x 8g x 32oc)
    const int by2 = bid >> 4, icb = bid & 15;
    const int by = by2 >> 1, h2 = by2 & 1;
    const int oc0 = by * 64 + h2 * 32, ic0 = icb * 32;
    const int ocl = tid & 31, g = tid >> 5;        // g 0..7
    float sq4[4] = {};
    for (int m = 0; m < 36; ++m) {
      int r = m * 8 + g;                 // r = t*32+icl; t=m>>2, icl=8*(m&3)+g
      int t = r >> 5, icl = r & 31;
      float v = cw[(size_t)(t * IC_ + ic0 + icl) * OC_ + oc0 + ocl];  // 128B seg
      sq4[m & 3] += v * v;
      LA[m * 256 + ocl * 8 + g] = (_Float16)v;     // ktq == m, j == g
    }
    for (int b = 0; b < 8; ++b) {
      float p = 0.f;
      for (int s = 0; s < 4; ++s)
        p += sm2[b * IC_ + ic0 + g + 8 * s] * sq4[s];
      redall[(b * 8 + g) * 32 + ocl] = p;
    }
    __syncthreads();
    // Wtf: 1152 contiguous-per-wave b128 chunks
    _Float16* dst = Wtf + (size_t)(by * 16 + icb) * 18432;
    for (int it = 0; it < 5; ++it) {
      int c = it * 256 + tid;
      if (c < 1152) {
        int m = c >> 5, o2 = c & 31;
        *(half8*)(dst + (size_t)(m * 64 + h2 * 32 + o2) * 8) =
            *(const half8*)&LA[m * 256 + o2 * 8];
      }
    }
    // dpart: reduce over g
    const int bb = tid >> 5, o3 = tid & 31;
    float s = 0.f;
    for (int g2 = 0; g2 < 8; ++g2) s += redall[(bb * 8 + g2) * 32 + o3];
    dpart[(size_t)icb * 4096 + bb * OC_ + oc0 + o3] = s;
  } else {
    // ---------------- xsp role (R4-proven structure) ----------------
    _Float16* Xt = (_Float16*)smem;                // 32*520*2 = 33280 B
    const int rb = bid - 256;
    const int b = rb >> 5, h = rb & 31;
    for (int k = 0; k < 16; ++k) {
      int idx = k * 256 + tid;           // 512 ic * 8 w-quads
      int ic = idx >> 3, wc = (idx & 7) * 4;
      float4 v = *(const float4*)&x[((size_t)(b * IC_ + ic) * 32 + h) * 32 + wc];
      float s = sm[b * IC_ + ic];
      Xt[(wc + 0) * 520 + ic] = (_Float16)(v.x * s);
      Xt[(wc + 1) * 520 + ic] = (_Float16)(v.y * s);
      Xt[(wc + 2) * 520 + ic] = (_Float16)(v.z * s);
      Xt[(wc + 3) * 520 + ic] = (_Float16)(v.w * s);
    }
    __syncthreads();
    _Float16* xb = xsp + (size_t)b * 16 * 36992;
    const int r = h + 1;
    half8 z = {};
    for (int it = 0; it < 9; ++it) {     // 16 icb * 4 kkq * 34 C = 2176 chunks
      int c = it * 256 + tid;
      if (c < 2176) {
        int icb = c / 136, rem = c - 136 * icb, kkq = rem / 34, C = rem - 34 * kkq;
        half8 val = z;
        if (C != 0 && C != 33)
          val = *(const half8*)&Xt[(C - 1) * 520 + icb * 32 + kkq * 8];
        *(half8*)&xb[(size_t)icb * 36992 + (size_t)r * 1088 + kkq * 272 + C * 8] = val;
      }
    }
    if (h == 0 || h == 31) {             // zero top/bottom padded rows
      const int rz = (h == 0) ? 0 : 33;
      for (int it = 0; it < 9; ++it) {
        int c = it * 256 + tid;
        if (c < 2176) {
          int icb = c / 136, rem = c - 136 * icb, kkq = rem / 34, C = rem - 34 * kkq;
          *(half8*)&xb[(size_t)icb * 36992 + (size_t)rz * 1088 + kkq * 272 + C * 8] = z;
        }
      }
    }
  }
}

// ---- conv: block 64oc x 128px (4 rows), grid (by 8, bx 8, b 8) = 512 ----
// gridDim.x == 8 and x == by  =>  XCD = linear_id % 8 = by: all 64 blocks
// sharing a by weight-slice (590 KB) run on one XCD -> A reads hit L2.
// Wave (wm,wn): 32oc x 64px (2 rows), acc[2]x16, an[] register A-prefetch.
__global__ __launch_bounds__(256) void conv_kernel(
    const _Float16* __restrict__ Wtf,   // [8 by][16 icb][36 ktq][64 oc][8]
    const _Float16* __restrict__ xsp,   // [8 b][16 icb][34 r][2 kk][2 kq][34 C][8]
    const float* __restrict__ dpart,    // [16 icb][8 b][512 oc]
    float* __restrict__ out) {          // [8][512][32][32]
  const int by = blockIdx.x, bx = blockIdx.y, b = blockIdx.z;
  const int tid = threadIdx.x, lane = tid & 63, w = tid >> 6;
  const int wm = w & 1, wn = w >> 1;    // wn: which 2-row half
  const int n = lane & 31, kq = lane >> 5;
  const int h0 = bx * 4;                // output rows h0..h0+3; padded h0..h0+5

  __shared__ _Float16 Xb[2][6528];      // 816 chunks x 8 halfs = 13056 B each
  __shared__ float redd[4][64];
  __shared__ float dvl[64];

  const _Float16* gX = xsp + (size_t)b * 16 * 36992 + (size_t)h0 * 1088;
  const _Float16* gA = Wtf + (size_t)(by * 16) * 18432;
  const int aoff = kq * 512 + (wm * 32 + n) * 8;

  // prologue: stage X(0), load A(0)
  for (int i = 0; i < 4; ++i) {
    int c = i * 256 + tid;
    if (c < 816) g2l(gX + (size_t)c * 8, &Xb[0][c * 8]);
  }
  half8 a[9][2], an[9][2];
#pragma unroll
  for (int t = 0; t < 9; ++t)
#pragma unroll
    for (int kk = 0; kk < 2; ++kk)
      a[t][kk] = *(const half8*)(gA + aoff + (t * 2 + kk) * 1024);

  floatx16 acc[2] = {};
  for (int icb = 0; icb < 16; ++icb) {
    const int cur = icb & 1;
    __syncthreads();                    // X(cur) staged & visible
    if (icb < 15) {                     // prefetch icb+1: A->regs, X->LDS
      const _Float16* gA1 = gA + (size_t)(icb + 1) * 18432 + aoff;
#pragma unroll
      for (int t = 0; t < 9; ++t)
#pragma unroll
        for (int kk = 0; kk < 2; ++kk)
          an[t][kk] = *(const half8*)(gA1 + (t * 2 + kk) * 1024);
      const _Float16* gX1 = gX + (size_t)(icb + 1) * 36992;
      for (int i = 0; i < 4; ++i) {
        int c = i * 256 + tid;
        if (c < 816) g2l(gX1 + (size_t)c * 8, &Xb[cur ^ 1][c * 8]);
      }
    }
    // compute: X frag at staged row (wn*2+s), col n+kw, k-half kk
    const _Float16* Xp = &Xb[cur][0] + (wn * 2) * 1088 + kq * 272 + n * 8;
#pragma unroll
    for (int s = 0; s < 4; ++s) {
#pragma unroll
      for (int kw = 0; kw < 3; ++kw) {
#pragma unroll
        for (int kk = 0; kk < 2; ++kk) {
          half8 xv = *(const half8*)(Xp + s * 1088 + kk * 544 + kw * 8);
#pragma unroll
          for (int kh = 0; kh < 3; ++kh) {
            int j = s - kh;
            if (j >= 0 && j < 2)
              acc[j] = __builtin_amdgcn_mfma_f32_32x32x16_f16(
                  a[kh * 3 + kw][kk], xv, acc[j], 0, 0, 0);
          }
        }
      }
    }
#pragma unroll
    for (int t = 0; t < 9; ++t) { a[t][0] = an[t][0]; a[t][1] = an[t][1]; }
  }

  // epilogue: reduce dpart over 16 icb -> dv[64] in LDS, then plain stores
  __syncthreads();
  {
    const int oc_l = tid & 63, ig = tid >> 6;
    float s = 0.f;
    for (int k = 0; k < 4; ++k)
      s += dpart[(size_t)(ig * 4 + k) * 4096 + b * OC_ + by * 64 + oc_l];
    redd[ig][oc_l] = s;
  }
  __syncthreads();
  if (tid < 64)
    dvl[tid] = rsqrtf(redd[0][tid] + redd[1][tid] + redd[2][tid] +
                      redd[3][tid] + 1e-8f);
  __syncthreads();
  // D col(px)=n, row(oc)=(rg&3)+8*(rg>>2)+4*kq
  const int oc0 = by * 64 + wm * 32;
  const int r0 = h0 + wn * 2;
#pragma unroll
  for (int rg = 0; rg < 16; ++rg) {
    const int row = (rg & 3) + 8 * (rg >> 2) + 4 * kq;
    const float dv = dvl[wm * 32 + row];
    float* op = out + ((size_t)b * OC_ + oc0 + row) * 1024 + r0 * 32 + n;
    op[0]  = acc[0][rg] * dv;
    op[32] = acc[1][rg] * dv;
  }
}

extern "C" void kernel_launch(void* const* d_in, const int* in_sizes, int n_in,
                              void* d_out, int out_size, void* d_ws, size_t ws_size,
                              hipStream_t stream) {
  const float* x       = (const float*)d_in[0];
  const float* w       = (const float*)d_in[1];
  const float* conv_w  = (const float*)d_in[2];
  const float* dense_w = (const float*)d_in[3];
  const float* dense_b = (const float*)d_in[4];
  float* out = (float*)d_out;

  char* ws = (char*)d_ws;
  float*    sm    = (float*)ws;                        // 16 KB
  float*    sm2   = (float*)(ws + (16 << 10));         // 16 KB
  float*    dpart = (float*)(ws + (32 << 10));         // 256 KB
  _Float16* Wtf   = (_Float16*)(ws + (288 << 10));               // 4,718,592 B
  _Float16* xsp   = (_Float16*)(ws + (288 << 10) + 4718592);     // 9,469,952 B

  style_kernel<<<dim3(8, B_), 256, 0, stream>>>(w, dense_w, dense_b, sm, sm2);
  prep_kernel<<<512, 256, 0, stream>>>(conv_w, x, sm, sm2, Wtf, dpart, xsp);
  conv_kernel<<<dim3(8, 8, B_), 256, 0, stream>>>(Wtf, xsp, dpart, out);
}